// Round 10
// baseline (56.402 us; speedup 1.0000x reference)
//
#include <hip/hip_runtime.h>

typedef float f32x4 __attribute__((ext_vector_type(4)));

#define BB 4
#define CC 3
#define HH 1024
#define WW 1024
#define NCHUNK (WW / 4)   // 256 float4 chunks per row
#define REP 2             // DIAGNOSTIC: run the row twice to exceed the 57us
                          // fill dispatches and surface in rocprof top-5.

__global__ __launch_bounds__(512) void dpmerge_kernel(
    const float* __restrict__ image,   // (B,C,H,W)
    const float* __restrict__ depth,   // (B,H,W)
    float* __restrict__ out)           // left (B,C,H,W) then right (B,C,H,W)
{
    const int row  = blockIdx.x;       // 0 .. B*H-1
    const int b    = row >> 10;
    const int h    = row & (HH - 1);
    const int tid  = threadIdx.x;      // 0..511
    const int vtid = tid & 255;        // pixel-group id within the view
    const bool isL = tid < 256;        // wave-uniform view split
    const int x0   = 4 * vtid;         // this thread's 4 output pixels
    const float xb = (float)x0;

    const size_t chStride = (size_t)HH * WW;
    const size_t imgBase  = ((size_t)b * CC) * chStride + (size_t)h * WW;
    const size_t NV       = (size_t)BB * CC * chStride;   // right-view offset

    const f32x4* Drow = reinterpret_cast<const f32x4*>(depth + (size_t)row * WW);
    const f32x4* I0   = reinterpret_cast<const f32x4*>(image + imgBase);
    const f32x4* I1   = reinterpret_cast<const f32x4*>(image + imgBase + chStride);
    const f32x4* I2   = reinterpret_cast<const f32x4*>(image + imgBase + 2 * chStride);

    const int cbase = isL ? (vtid - 2) : vtid;

    for (int rep = 0; rep < REP; ++rep) {
        // Prevent cross-iteration CSE: force genuine reload + recompute + restore.
        asm volatile("" ::: "memory");

        float dw[12], im0[12], im1[12], im2[12];
#pragma unroll
        for (int i = 0; i < 3; ++i) {
            int c = cbase + i;
            c = c < 0 ? 0 : (c > NCHUNK - 1 ? NCHUNK - 1 : c);
            const f32x4 dv = Drow[c];
            const f32x4 v0 = I0[c];
            const f32x4 v1 = I1[c];
            const f32x4 v2 = I2[c];
            dw [4*i+0] = dv.x; dw [4*i+1] = dv.y; dw [4*i+2] = dv.z; dw [4*i+3] = dv.w;
            im0[4*i+0] = v0.x; im0[4*i+1] = v0.y; im0[4*i+2] = v0.z; im0[4*i+3] = v0.w;
            im1[4*i+0] = v1.x; im1[4*i+1] = v1.y; im1[4*i+2] = v1.z; im1[4*i+3] = v1.w;
            im2[4*i+0] = v2.x; im2[4*i+1] = v2.y; im2[4*i+2] = v2.z; im2[4*i+3] = v2.w;
        }

        float pos[12];
        if (isL) {
            if (x0 < 8) {                        // vtid 0,1 only: s = x0-8+u < 0
#pragma unroll
                for (int u = 0; u < 8; ++u)
                    if (x0 - 8 + u < 0) dw[u] = 1e30f;
            }
#pragma unroll
            for (int u = 0; u < 12; ++u)         // s = x0-8+u, pos = fl(s) + d
                pos[u] = (xb + (float)(u - 8)) + dw[u];
        } else {
            if (x0 + 11 >= WW) {                 // vtid 254,255: s = x0+u >= W
#pragma unroll
                for (int u = 4; u < 12; ++u)
                    if (x0 + u >= WW) dw[u] = 1e30f;
            }
#pragma unroll
            for (int u = 0; u < 12; ++u)         // s = x0+u, pos = fl(s) - d
                pos[u] = (xb + (float)u) - dw[u];
        }

        f32x4 oc0, oc1, oc2;
#pragma unroll
        for (int j = 0; j < 4; ++j) {
            const float xf = xb + (float)j;
            float cw = 0.f, a0 = 0.f, a1 = 0.f, a2 = 0.f;
#pragma unroll
            for (int i = 0; i < 9; ++i) {
                const int   u  = j + i;
                const float t  = pos[u] - xf;
                const float wt = fmaxf(1.0f - fabsf(t), 0.0f);
                cw += wt;
                a0 = fmaf(im0[u], wt, a0);
                a1 = fmaf(im1[u], wt, a1);
                a2 = fmaf(im2[u], wt, a2);
            }
            const float inv = __builtin_amdgcn_rcpf(fmaxf(cw, 1e-30f));
            oc0[j] = a0 * inv;
            oc1[j] = a1 * inv;
            oc2[j] = a2 * inv;
        }

        const size_t obase = isL ? imgBase : (NV + imgBase);
        __builtin_nontemporal_store(oc0, reinterpret_cast<f32x4*>(out + obase + x0));
        __builtin_nontemporal_store(oc1, reinterpret_cast<f32x4*>(out + obase + chStride + x0));
        __builtin_nontemporal_store(oc2, reinterpret_cast<f32x4*>(out + obase + 2 * chStride + x0));
    }
}

extern "C" void kernel_launch(void* const* d_in, const int* in_sizes, int n_in,
                              void* d_out, int out_size, void* d_ws, size_t ws_size,
                              hipStream_t stream) {
    const float* image = (const float*)d_in[0];
    const float* depth = (const float*)d_in[1];
    float* out = (float*)d_out;
    (void)in_sizes; (void)n_in; (void)out_size; (void)d_ws; (void)ws_size;

    dim3 grid(BB * HH);   // 4096 rows, one block per row, both views
    dim3 block(512);
    hipLaunchKernelGGL(dpmerge_kernel, grid, block, 0, stream, image, depth, out);
}

// Round 11
// 33.922 us; speedup vs baseline: 1.6627x; 1.6627x over previous
//
#include <hip/hip_runtime.h>

typedef float f32x4 __attribute__((ext_vector_type(4)));

#define BB 4
#define CC 3
#define HH 1024
#define WW 1024
#define NCHUNK (WW / 4)   // 256 float4 chunks per row

__global__ __launch_bounds__(512) void dpmerge_kernel(
    const float* __restrict__ image,   // (B,C,H,W)
    const float* __restrict__ depth,   // (B,H,W)
    float* __restrict__ out)           // left (B,C,H,W) then right (B,C,H,W)
{
    const int row  = blockIdx.x;       // 0 .. B*H-1
    const int b    = row >> 10;
    const int h    = row & (HH - 1);
    const int tid  = threadIdx.x;      // 0..511
    const int vtid = tid & 255;        // pixel-group id within the view
    const bool isL = tid < 256;        // wave-uniform view split
    const int x0   = 4 * vtid;         // this thread's 4 output pixels
    const float xb = (float)x0;

    const size_t chStride = (size_t)HH * WW;
    const size_t imgBase  = ((size_t)b * CC) * chStride + (size_t)h * WW;
    const size_t NV       = (size_t)BB * CC * chStride;   // right-view offset

    const f32x4* Drow = reinterpret_cast<const f32x4*>(depth + (size_t)row * WW);
    const f32x4* I0   = reinterpret_cast<const f32x4*>(image + imgBase);
    const f32x4* I1   = reinterpret_cast<const f32x4*>(image + imgBase + chStride);
    const f32x4* I2   = reinterpret_cast<const f32x4*>(image + imgBase + 2 * chStride);

    // Source window (12 wide):
    //   left view : s in [x0-8, x0+3]  -> chunks vtid-2 .. vtid
    //   right view: s in [x0,   x0+11] -> chunks vtid   .. vtid+2
    const int cbase = isL ? (vtid - 2) : vtid;

    float dw[12], im0[12], im1[12], im2[12];
#pragma unroll
    for (int i = 0; i < 3; ++i) {
        int c = cbase + i;
        c = c < 0 ? 0 : (c > NCHUNK - 1 ? NCHUNK - 1 : c);
        const f32x4 dv = Drow[c];
        const f32x4 v0 = I0[c];
        const f32x4 v1 = I1[c];
        const f32x4 v2 = I2[c];
        dw [4*i+0] = dv.x; dw [4*i+1] = dv.y; dw [4*i+2] = dv.z; dw [4*i+3] = dv.w;
        im0[4*i+0] = v0.x; im0[4*i+1] = v0.y; im0[4*i+2] = v0.z; im0[4*i+3] = v0.w;
        im1[4*i+0] = v1.x; im1[4*i+1] = v1.y; im1[4*i+2] = v1.z; im1[4*i+3] = v1.w;
        im2[4*i+0] = v2.x; im2[4*i+1] = v2.y; im2[4*i+2] = v2.z; im2[4*i+3] = v2.w;
    }

    // Boundary poison (depth -> 1e30 makes the hat weight exactly 0).
    float pos[12];
    if (isL) {
        if (x0 < 8) {                        // vtid 0,1 only: s = x0-8+u < 0
#pragma unroll
            for (int u = 0; u < 8; ++u)
                if (x0 - 8 + u < 0) dw[u] = 1e30f;
        }
#pragma unroll
        for (int u = 0; u < 12; ++u)         // s = x0-8+u, pos = fl(s) + d
            pos[u] = (xb + (float)(u - 8)) + dw[u];
    } else {
        if (x0 + 11 >= WW) {                 // vtid 254,255: s = x0+u >= W
#pragma unroll
            for (int u = 4; u < 12; ++u)
                if (x0 + u >= WW) dw[u] = 1e30f;
        }
#pragma unroll
        for (int u = 0; u < 12; ++u)         // s = x0+u, pos = fl(s) - d
            pos[u] = (xb + (float)u) - dw[u];
    }

    // Pixel x0+j gathers window idx u = j..j+8 in both views.
    f32x4 oc0, oc1, oc2;
#pragma unroll
    for (int j = 0; j < 4; ++j) {
        const float xf = xb + (float)j;
        float cw = 0.f, a0 = 0.f, a1 = 0.f, a2 = 0.f;
#pragma unroll
        for (int i = 0; i < 9; ++i) {
            const int   u  = j + i;
            const float t  = pos[u] - xf;
            const float wt = fmaxf(1.0f - fabsf(t), 0.0f);
            cw += wt;
            a0 = fmaf(im0[u], wt, a0);
            a1 = fmaf(im1[u], wt, a1);
            a2 = fmaf(im2[u], wt, a2);
        }
        const float inv = __builtin_amdgcn_rcpf(fmaxf(cw, 1e-30f));
        oc0[j] = a0 * inv;
        oc1[j] = a1 * inv;
        oc2[j] = a2 * inv;
    }

    const size_t obase = isL ? imgBase : (NV + imgBase);
    *reinterpret_cast<f32x4*>(out + obase + x0)                = oc0;
    *reinterpret_cast<f32x4*>(out + obase + chStride + x0)     = oc1;
    *reinterpret_cast<f32x4*>(out + obase + 2 * chStride + x0) = oc2;
}

extern "C" void kernel_launch(void* const* d_in, const int* in_sizes, int n_in,
                              void* d_out, int out_size, void* d_ws, size_t ws_size,
                              hipStream_t stream) {
    const float* image = (const float*)d_in[0];
    const float* depth = (const float*)d_in[1];
    float* out = (float*)d_out;
    (void)in_sizes; (void)n_in; (void)out_size; (void)d_ws; (void)ws_size;

    dim3 grid(BB * HH);   // 4096 rows, one block per row, both views
    dim3 block(512);
    hipLaunchKernelGGL(dpmerge_kernel, grid, block, 0, stream, image, depth, out);
}

// Round 12
// 32.822 us; speedup vs baseline: 1.7184x; 1.0335x over previous
//
#include <hip/hip_runtime.h>

typedef float f32x4 __attribute__((ext_vector_type(4)));

#define BB 4
#define CC 3
#define HH 1024
#define WW 1024
#define NCHUNK (WW / 4)   // 256 float4 chunks per row

// Best measured variant (R9): one 512-thread block per (b,h) row; threads
// 0-255 compute the left view, 256-511 the right view (wave-uniform split).
// Direct register gather (no LDS, no barrier); hat-function bilinear weights
// with bit-exact pos = fl(float(s) +- d); nontemporal f32x4 stores.
__global__ __launch_bounds__(512) void dpmerge_kernel(
    const float* __restrict__ image,   // (B,C,H,W)
    const float* __restrict__ depth,   // (B,H,W)
    float* __restrict__ out)           // left (B,C,H,W) then right (B,C,H,W)
{
    const int row  = blockIdx.x;       // 0 .. B*H-1
    const int b    = row >> 10;
    const int h    = row & (HH - 1);
    const int tid  = threadIdx.x;      // 0..511
    const int vtid = tid & 255;        // pixel-group id within the view
    const bool isL = tid < 256;        // wave-uniform view split
    const int x0   = 4 * vtid;         // this thread's 4 output pixels
    const float xb = (float)x0;

    const size_t chStride = (size_t)HH * WW;
    const size_t imgBase  = ((size_t)b * CC) * chStride + (size_t)h * WW;
    const size_t NV       = (size_t)BB * CC * chStride;   // right-view offset

    const f32x4* Drow = reinterpret_cast<const f32x4*>(depth + (size_t)row * WW);
    const f32x4* I0   = reinterpret_cast<const f32x4*>(image + imgBase);
    const f32x4* I1   = reinterpret_cast<const f32x4*>(image + imgBase + chStride);
    const f32x4* I2   = reinterpret_cast<const f32x4*>(image + imgBase + 2 * chStride);

    // Source window (12 wide):
    //   left view : s in [x0-8, x0+3]  -> chunks vtid-2 .. vtid
    //   right view: s in [x0,   x0+11] -> chunks vtid   .. vtid+2
    const int cbase = isL ? (vtid - 2) : vtid;

    float dw[12], im0[12], im1[12], im2[12];
#pragma unroll
    for (int i = 0; i < 3; ++i) {
        int c = cbase + i;
        c = c < 0 ? 0 : (c > NCHUNK - 1 ? NCHUNK - 1 : c);
        const f32x4 dv = Drow[c];
        const f32x4 v0 = I0[c];
        const f32x4 v1 = I1[c];
        const f32x4 v2 = I2[c];
        dw [4*i+0] = dv.x; dw [4*i+1] = dv.y; dw [4*i+2] = dv.z; dw [4*i+3] = dv.w;
        im0[4*i+0] = v0.x; im0[4*i+1] = v0.y; im0[4*i+2] = v0.z; im0[4*i+3] = v0.w;
        im1[4*i+0] = v1.x; im1[4*i+1] = v1.y; im1[4*i+2] = v1.z; im1[4*i+3] = v1.w;
        im2[4*i+0] = v2.x; im2[4*i+1] = v2.y; im2[4*i+2] = v2.z; im2[4*i+3] = v2.w;
    }

    // Boundary poison (depth -> 1e30 makes the hat weight exactly 0).
    float pos[12];
    if (isL) {
        if (x0 < 8) {                        // vtid 0,1 only: s = x0-8+u < 0
#pragma unroll
            for (int u = 0; u < 8; ++u)
                if (x0 - 8 + u < 0) dw[u] = 1e30f;
        }
#pragma unroll
        for (int u = 0; u < 12; ++u)         // s = x0-8+u, pos = fl(s) + d
            pos[u] = (xb + (float)(u - 8)) + dw[u];
    } else {
        if (x0 + 11 >= WW) {                 // vtid 254,255: s = x0+u >= W
#pragma unroll
            for (int u = 4; u < 12; ++u)
                if (x0 + u >= WW) dw[u] = 1e30f;
        }
#pragma unroll
        for (int u = 0; u < 12; ++u)         // s = x0+u, pos = fl(s) - d
            pos[u] = (xb + (float)u) - dw[u];
    }

    // Pixel x0+j gathers window idx u = j..j+8 in both views.
    f32x4 oc0, oc1, oc2;
#pragma unroll
    for (int j = 0; j < 4; ++j) {
        const float xf = xb + (float)j;
        float cw = 0.f, a0 = 0.f, a1 = 0.f, a2 = 0.f;
#pragma unroll
        for (int i = 0; i < 9; ++i) {
            const int   u  = j + i;
            const float t  = pos[u] - xf;
            const float wt = fmaxf(1.0f - fabsf(t), 0.0f);
            cw += wt;
            a0 = fmaf(im0[u], wt, a0);
            a1 = fmaf(im1[u], wt, a1);
            a2 = fmaf(im2[u], wt, a2);
        }
        const float inv = __builtin_amdgcn_rcpf(fmaxf(cw, 1e-30f));
        oc0[j] = a0 * inv;
        oc1[j] = a1 * inv;
        oc2[j] = a2 * inv;
    }

    const size_t obase = isL ? imgBase : (NV + imgBase);
    __builtin_nontemporal_store(oc0, reinterpret_cast<f32x4*>(out + obase + x0));
    __builtin_nontemporal_store(oc1, reinterpret_cast<f32x4*>(out + obase + chStride + x0));
    __builtin_nontemporal_store(oc2, reinterpret_cast<f32x4*>(out + obase + 2 * chStride + x0));
}

extern "C" void kernel_launch(void* const* d_in, const int* in_sizes, int n_in,
                              void* d_out, int out_size, void* d_ws, size_t ws_size,
                              hipStream_t stream) {
    const float* image = (const float*)d_in[0];
    const float* depth = (const float*)d_in[1];
    float* out = (float*)d_out;
    (void)in_sizes; (void)n_in; (void)out_size; (void)d_ws; (void)ws_size;

    dim3 grid(BB * HH);   // 4096 rows, one block per row, both views
    dim3 block(512);
    hipLaunchKernelGGL(dpmerge_kernel, grid, block, 0, stream, image, depth, out);
}